// Round 6
// baseline (1465.622 us; speedup 1.0000x reference)
//
#include <hip/hip_runtime.h>
#include <hip/hip_bf16.h>

typedef float f2 __attribute__((ext_vector_type(2)));
typedef float f4 __attribute__((ext_vector_type(4)));
typedef _Float16 hf;
typedef hf hf2 __attribute__((ext_vector_type(2)));
typedef hf hf4 __attribute__((ext_vector_type(4)));

#define N_NODES 50000
#define N_EDGES 800000
#define CH 128
#define N_GRAPHS 512
#define NPB 32   // dst nodes per block (aligned), LDS accum = 32x128 f32 = 16KB

// ---------------- degree histogram ----------------
__global__ __launch_bounds__(256) void deg_hist_k(const int* __restrict__ dst,
                                                  int* __restrict__ deg) {
    int e = blockIdx.x * 256 + threadIdx.x;
    if (e < N_EDGES) atomicAdd(&deg[dst[e]], 1);
}

// ---------------- 3-step exclusive scan over 50000 ints ----------------
__global__ __launch_bounds__(1024) void scan1_k(const int* __restrict__ deg,
                                                int* __restrict__ tmp,
                                                int* __restrict__ bsum, int n) {
    __shared__ int s[1024];
    int tid = threadIdx.x;
    int gid = blockIdx.x * 1024 + tid;
    int v = (gid < n) ? deg[gid] : 0;
    s[tid] = v;
    __syncthreads();
    for (int off = 1; off < 1024; off <<= 1) {
        int t = (tid >= off) ? s[tid - off] : 0;
        __syncthreads();
        s[tid] += t;
        __syncthreads();
    }
    if (gid < n) tmp[gid] = s[tid];
    if (tid == 1023) bsum[blockIdx.x] = s[tid];
}

__global__ void scan2_k(int* __restrict__ bsum, int nb) {
    int lane = threadIdx.x;  // one wave of 64
    int v = (lane < nb) ? bsum[lane] : 0;
    for (int off = 1; off < 64; off <<= 1) {
        int t = __shfl_up(v, off);
        if (lane >= off) v += t;
    }
    if (lane < nb) bsum[lane] = v;
}

// writes row_ptr (exclusive), cursor copy, and dinv = rsqrt(deg+1)
__global__ __launch_bounds__(1024) void scan3_k(const int* __restrict__ tmp,
                                                const int* __restrict__ bsum,
                                                const int* __restrict__ deg,
                                                int* __restrict__ rowp,
                                                int* __restrict__ cursor,
                                                float* __restrict__ dinv, int n) {
    int gid = blockIdx.x * 1024 + threadIdx.x;
    if (gid >= n) return;
    int off = blockIdx.x ? bsum[blockIdx.x - 1] : 0;
    int incl = tmp[gid] + off;
    rowp[gid + 1] = incl;
    cursor[gid] = incl - deg[gid];
    dinv[gid] = rsqrtf((float)deg[gid] + 1.0f);  // +1 for self-loop
    if (gid == 0) rowp[0] = 0;
}

// ------- CSR fill: packed entry = src | ((dst & (NPB-1)) << 16) -------
__global__ __launch_bounds__(256) void csr_fill_k(const int* __restrict__ src,
                                                  const int* __restrict__ dst,
                                                  int* __restrict__ cursor,
                                                  unsigned* __restrict__ csrp) {
    int e = blockIdx.x * 256 + threadIdx.x;
    if (e < N_EDGES) {
        int d = dst[e];
        int pos = atomicAdd(&cursor[d], 1);
        csrp[pos] = (unsigned)src[e] | (((unsigned)d & (NPB - 1)) << 16);
    }
}

// ------- GEMM: out[M,128] = (A[M,128] @ W[128,128]) * dinv[row], fp16 out ----
template <typename TA>
__global__ __launch_bounds__(256) void gemm_scaled_k(const TA* __restrict__ A,
                                                     const float* __restrict__ W,
                                                     const float* __restrict__ dinv,
                                                     hf* __restrict__ out, int M) {
    __shared__ float sA[64][132];   // padded
    __shared__ float sW[128][68];
    int tid = threadIdx.x;
    int row0 = blockIdx.x * 64;
    int col0 = blockIdx.y * 64;

    #pragma unroll
    for (int rep = 0; rep < 8; ++rep) {
        int idx = rep * 256 + tid;       // 0..2047, 4 ch each
        int r = idx >> 5, k4 = idx & 31;
        f4 vf = {0.f, 0.f, 0.f, 0.f};
        int row = row0 + r;
        if (row < M) {
            if constexpr (sizeof(TA) == 4) {
                vf = *(const f4*)&A[row * 128 + k4 * 4];
            } else {
                hf4 v = *(const hf4*)&A[row * 128 + k4 * 4];
                vf = f4{(float)v[0], (float)v[1], (float)v[2], (float)v[3]};
            }
        }
        *(f4*)&sA[r][k4 * 4] = vf;
    }
    #pragma unroll
    for (int rep = 0; rep < 8; ++rep) {
        int idx = rep * 256 + tid;       // 0..2047
        int k = idx >> 4, c4 = idx & 15;
        f4 v = *(const f4*)&W[k * 128 + col0 + c4 * 4];
        *(f4*)&sW[k][c4 * 4] = v;
    }
    __syncthreads();

    int tx = tid & 15, ty = tid >> 4;
    float acc[4][4] = {};
    for (int k = 0; k < 128; k += 4) {
        f4 a[4], b[4];
        #pragma unroll
        for (int i = 0; i < 4; ++i) a[i] = *(const f4*)&sA[ty * 4 + i][k];
        #pragma unroll
        for (int kk = 0; kk < 4; ++kk) b[kk] = *(const f4*)&sW[k + kk][tx * 4];
        #pragma unroll
        for (int i = 0; i < 4; ++i)
            #pragma unroll
            for (int j = 0; j < 4; ++j)
                acc[i][j] += a[i][0] * b[0][j] + a[i][1] * b[1][j] +
                             a[i][2] * b[2][j] + a[i][3] * b[3][j];
    }
    #pragma unroll
    for (int i = 0; i < 4; ++i) {
        int row = row0 + ty * 4 + i;
        if (row < M) {
            float dv = dinv[row];
            hf4 o = {(hf)(acc[i][0] * dv), (hf)(acc[i][1] * dv),
                     (hf)(acc[i][2] * dv), (hf)(acc[i][3] * dv)};
            *(hf4*)&out[row * 128 + col0 + tx * 4] = o;
        }
    }
}

// ---------------- edge-parallel aggregate with LDS accumulators ----------
// Block owns NPB=32 consecutive dst nodes; their CSR edges are contiguous.
// LDS acc initialized with self-loop row (xws pre-scaled by dinv). 8 half-
// waves stream the edge strip: independent row loads 8-deep, per-lane
// ds_add_f32 into the dst accumulator. MODE 0: write h rows. MODE 1: fused
// bias/ReLU + dot(Wfc) + mean-pool atomics.
#define UNPK(p, vq) do { \
        int dl_ = (int)((p) >> 16); \
        atomicAdd(&lds[dl_][hl * 4 + 0], (float)(vq)[0]); \
        atomicAdd(&lds[dl_][hl * 4 + 1], (float)(vq)[1]); \
        atomicAdd(&lds[dl_][hl * 4 + 2], (float)(vq)[2]); \
        atomicAdd(&lds[dl_][hl * 4 + 3], (float)(vq)[3]); } while (0)

template <int MODE>
__global__ __launch_bounds__(256) void agg_k(const hf* __restrict__ xws,
                                             const float* __restrict__ dinv,
                                             const int* __restrict__ rowp,
                                             const unsigned* __restrict__ csrp,
                                             const float* __restrict__ bias,
                                             const int* __restrict__ batch,
                                             const float* __restrict__ Wfc,
                                             float* __restrict__ pool,
                                             float* __restrict__ cntp,
                                             hf* __restrict__ h) {
    __shared__ float lds[NPB][CH];
    const hf4* rows = (const hf4*)xws;
    int n0 = blockIdx.x * NPB;
    int tid = threadIdx.x;
    int wid = tid >> 6, lane = tid & 63;

    // init accumulators with self-loop row (already dinv[src]-scaled)
    #pragma unroll
    for (int i = 0; i < 8; ++i) {
        int nl = i * 4 + wid;
        int node = n0 + nl;
        if (node < N_NODES) {
            hf2 v = ((const hf2*)xws)[node * 64 + lane];
            lds[nl][lane * 2 + 0] = (float)v[0];
            lds[nl][lane * 2 + 1] = (float)v[1];
        }
    }
    __syncthreads();

    int nTop = (n0 + NPB < N_NODES) ? n0 + NPB : N_NODES;
    int e0 = rowp[n0], e1 = rowp[nTop];
    int hw = tid >> 5;           // 8 half-wave strips
    int hl = tid & 31;           // hf4 slot within 256B row
    int hbase = lane & 32;
    int per = ((e1 - e0) + 7) >> 3;
    int base = e0 + hw * per;
    int lim = base + per < e1 ? base + per : e1;

    for (int s = base; s < lim; s += 32) {
        int m = lim - s; if (m > 32) m = 32;
        unsigned myP = (hl < m) ? csrp[s + hl] : 0u;
        int j = 0;
        for (; j + 8 <= m; j += 8) {
            unsigned p0 = __shfl(myP, hbase + j + 0);
            unsigned p1 = __shfl(myP, hbase + j + 1);
            unsigned p2 = __shfl(myP, hbase + j + 2);
            unsigned p3 = __shfl(myP, hbase + j + 3);
            unsigned p4 = __shfl(myP, hbase + j + 4);
            unsigned p5 = __shfl(myP, hbase + j + 5);
            unsigned p6 = __shfl(myP, hbase + j + 6);
            unsigned p7 = __shfl(myP, hbase + j + 7);
            hf4 v0 = rows[(p0 & 0xFFFFu) * 32 + hl];
            hf4 v1 = rows[(p1 & 0xFFFFu) * 32 + hl];
            hf4 v2 = rows[(p2 & 0xFFFFu) * 32 + hl];
            hf4 v3 = rows[(p3 & 0xFFFFu) * 32 + hl];
            hf4 v4 = rows[(p4 & 0xFFFFu) * 32 + hl];
            hf4 v5 = rows[(p5 & 0xFFFFu) * 32 + hl];
            hf4 v6 = rows[(p6 & 0xFFFFu) * 32 + hl];
            hf4 v7 = rows[(p7 & 0xFFFFu) * 32 + hl];
            UNPK(p0, v0); UNPK(p1, v1); UNPK(p2, v2); UNPK(p3, v3);
            UNPK(p4, v4); UNPK(p5, v5); UNPK(p6, v6); UNPK(p7, v7);
        }
        if (j + 4 <= m) {
            unsigned p0 = __shfl(myP, hbase + j + 0);
            unsigned p1 = __shfl(myP, hbase + j + 1);
            unsigned p2 = __shfl(myP, hbase + j + 2);
            unsigned p3 = __shfl(myP, hbase + j + 3);
            hf4 v0 = rows[(p0 & 0xFFFFu) * 32 + hl];
            hf4 v1 = rows[(p1 & 0xFFFFu) * 32 + hl];
            hf4 v2 = rows[(p2 & 0xFFFFu) * 32 + hl];
            hf4 v3 = rows[(p3 & 0xFFFFu) * 32 + hl];
            UNPK(p0, v0); UNPK(p1, v1); UNPK(p2, v2); UNPK(p3, v3);
            j += 4;
        }
        for (; j < m; ++j) {
            unsigned p0 = __shfl(myP, hbase + j);
            hf4 v0 = rows[(p0 & 0xFFFFu) * 32 + hl];
            UNPK(p0, v0);
        }
    }
    __syncthreads();

    // epilogue: wave per node, f2 per lane
    #pragma unroll
    for (int i = 0; i < 8; ++i) {
        int nl = i * 4 + wid;
        int node = n0 + nl;
        if (node >= N_NODES) continue;
        float a0 = lds[nl][lane * 2 + 0];
        float a1 = lds[nl][lane * 2 + 1];
        float dn = dinv[node];
        f2 bb = *(const f2*)&bias[lane * 2];
        float o0 = fmaxf(a0 * dn + bb[0], 0.f);
        float o1 = fmaxf(a1 * dn + bb[1], 0.f);
        if constexpr (MODE == 0) {
            ((hf2*)h)[node * 64 + lane] = hf2{(hf)o0, (hf)o1};
        } else {
            f2 wf = *(const f2*)&Wfc[lane * 2];
            float p = o0 * wf[0] + o1 * wf[1];
            #pragma unroll
            for (int off = 32; off > 0; off >>= 1) p += __shfl_xor(p, off);
            if (lane == 0) {
                int g = batch[node];
                atomicAdd(&pool[g], p);
                atomicAdd(&cntp[g], 1.0f);
            }
        }
    }
}

__global__ void finalize_k(const float* __restrict__ pool,
                           const float* __restrict__ cnt,
                           const float* __restrict__ bfc,
                           float* __restrict__ out) {
    int g = blockIdx.x * blockDim.x + threadIdx.x;
    if (g < N_GRAPHS) out[g] = pool[g] / fmaxf(cnt[g], 1.0f) + bfc[0];
}

extern "C" void kernel_launch(void* const* d_in, const int* in_sizes, int n_in,
                              void* d_out, int out_size, void* d_ws, size_t ws_size,
                              hipStream_t stream) {
    const float* x    = (const float*)d_in[0];
    const int*   ei   = (const int*)d_in[1];   // [2, E] flat, int32
    const int*   batch= (const int*)d_in[2];
    const float* W1   = (const float*)d_in[3];
    const float* b1   = (const float*)d_in[4];
    const float* W2   = (const float*)d_in[5];
    const float* b2   = (const float*)d_in[6];
    const float* Wfc  = (const float*)d_in[7];
    const float* bfc  = (const float*)d_in[8];
    float* out = (float*)d_out;

    const int* src = ei;
    const int* dst = ei + N_EDGES;

    // workspace carve-up
    char* w = (char*)d_ws;
    float*    dinv   = (float*)w;    w += 50048 * 4;
    int*      deg    = (int*)w;      w += 50048 * 4;
    int*      rowp   = (int*)w;      w += 50176 * 4;   // 50001 used, padded
    int*      cursor = (int*)w;      w += 50048 * 4;
    int*      stmp   = (int*)w;      w += 50048 * 4;
    int*      bsum   = (int*)w;      w += 256 * 4;
    unsigned* csrp   = (unsigned*)w; w += N_EDGES * 4;
    hf*       xws1   = (hf*)w;       w += (size_t)N_NODES * 128 * 2;
    hf*       h1     = (hf*)w;       w += (size_t)N_NODES * 128 * 2;
    hf*       xws2   = (hf*)w;       w += (size_t)N_NODES * 128 * 2;
    float*    pool   = (float*)w;    w += 512 * 4;
    float*    cnt    = (float*)w;    w += 512 * 4;

    hipMemsetAsync(deg, 0, N_NODES * sizeof(int), stream);
    hipMemsetAsync(pool, 0, 2 * 512 * sizeof(float), stream);  // pool + cnt

    int eb = (N_EDGES + 255) / 256;
    deg_hist_k<<<eb, 256, 0, stream>>>(dst, deg);

    int nb = (N_NODES + 1023) / 1024;   // 49
    scan1_k<<<nb, 1024, 0, stream>>>(deg, stmp, bsum, N_NODES);
    scan2_k<<<1, 64, 0, stream>>>(bsum, nb);
    scan3_k<<<nb, 1024, 0, stream>>>(stmp, bsum, deg, rowp, cursor, dinv, N_NODES);

    csr_fill_k<<<eb, 256, 0, stream>>>(src, dst, cursor, csrp);

    dim3 ggrid((N_NODES + 63) / 64, 2);
    gemm_scaled_k<float><<<ggrid, 256, 0, stream>>>(x, W1, dinv, xws1, N_NODES);

    int ab = (N_NODES + NPB - 1) / NPB;   // 1563 blocks, all co-resident
    agg_k<0><<<ab, 256, 0, stream>>>(xws1, dinv, rowp, csrp, b1,
                                     nullptr, nullptr, nullptr, nullptr, h1);

    gemm_scaled_k<hf><<<ggrid, 256, 0, stream>>>(h1, W2, dinv, xws2, N_NODES);

    agg_k<1><<<ab, 256, 0, stream>>>(xws2, dinv, rowp, csrp, b2,
                                     batch, Wfc, pool, cnt, nullptr);

    finalize_k<<<2, 256, 0, stream>>>(pool, cnt, bfc, out);
}

// Round 9
// 383.357 us; speedup vs baseline: 3.8231x; 3.8231x over previous
//
#include <hip/hip_runtime.h>
#include <hip/hip_bf16.h>

typedef float f2 __attribute__((ext_vector_type(2)));
typedef float f4 __attribute__((ext_vector_type(4)));
typedef _Float16 hf;
typedef hf hf2 __attribute__((ext_vector_type(2)));
typedef hf hf4 __attribute__((ext_vector_type(4)));
typedef hf hf8 __attribute__((ext_vector_type(8)));

#define N_NODES 50000
#define N_EDGES 800000
#define CH 128
#define N_GRAPHS 512

// ---------------- degree histogram ----------------
__global__ __launch_bounds__(256) void deg_hist_k(const int* __restrict__ dst,
                                                  int* __restrict__ deg) {
    int e = blockIdx.x * 256 + threadIdx.x;
    if (e < N_EDGES) atomicAdd(&deg[dst[e]], 1);
}

// ---------------- 3-step exclusive scan over 50000 ints ----------------
__global__ __launch_bounds__(1024) void scan1_k(const int* __restrict__ deg,
                                                int* __restrict__ tmp,
                                                int* __restrict__ bsum, int n) {
    __shared__ int s[1024];
    int tid = threadIdx.x;
    int gid = blockIdx.x * 1024 + tid;
    int v = (gid < n) ? deg[gid] : 0;
    s[tid] = v;
    __syncthreads();
    for (int off = 1; off < 1024; off <<= 1) {
        int t = (tid >= off) ? s[tid - off] : 0;
        __syncthreads();
        s[tid] += t;
        __syncthreads();
    }
    if (gid < n) tmp[gid] = s[tid];
    if (tid == 1023) bsum[blockIdx.x] = s[tid];
}

__global__ void scan2_k(int* __restrict__ bsum, int nb) {
    int lane = threadIdx.x;  // one wave of 64
    int v = (lane < nb) ? bsum[lane] : 0;
    for (int off = 1; off < 64; off <<= 1) {
        int t = __shfl_up(v, off);
        if (lane >= off) v += t;
    }
    if (lane < nb) bsum[lane] = v;
}

// writes row_ptr (exclusive), cursor copy, and dinv = rsqrt(deg+1)
__global__ __launch_bounds__(1024) void scan3_k(const int* __restrict__ tmp,
                                                const int* __restrict__ bsum,
                                                const int* __restrict__ deg,
                                                int* __restrict__ rowp,
                                                int* __restrict__ cursor,
                                                float* __restrict__ dinv, int n) {
    int gid = blockIdx.x * 1024 + threadIdx.x;
    if (gid >= n) return;
    int off = blockIdx.x ? bsum[blockIdx.x - 1] : 0;
    int incl = tmp[gid] + off;
    rowp[gid + 1] = incl;
    cursor[gid] = incl - deg[gid];
    dinv[gid] = rsqrtf((float)deg[gid] + 1.0f);  // +1 for self-loop
    if (gid == 0) rowp[0] = 0;
}

// ---------------- CSR fill (src ids bucketed by dst) ----------------
__global__ __launch_bounds__(256) void csr_fill_k(const int* __restrict__ src,
                                                  const int* __restrict__ dst,
                                                  int* __restrict__ cursor,
                                                  int* __restrict__ csr) {
    int e = blockIdx.x * 256 + threadIdx.x;
    if (e < N_EDGES) {
        int d = dst[e];
        int pos = atomicAdd(&cursor[d], 1);
        csr[pos] = src[e];
    }
}

// ------- GEMM: out[M,128] = (A[M,128] @ W[128,128]) * dinv[row], fp16 out ----
template <typename TA>
__global__ __launch_bounds__(256) void gemm_scaled_k(const TA* __restrict__ A,
                                                     const float* __restrict__ W,
                                                     const float* __restrict__ dinv,
                                                     hf* __restrict__ out, int M) {
    __shared__ float sA[64][132];   // padded
    __shared__ float sW[128][68];
    int tid = threadIdx.x;
    int row0 = blockIdx.x * 64;
    int col0 = blockIdx.y * 64;

    #pragma unroll
    for (int rep = 0; rep < 8; ++rep) {
        int idx = rep * 256 + tid;       // 0..2047, 4 ch each
        int r = idx >> 5, k4 = idx & 31;
        f4 vf = {0.f, 0.f, 0.f, 0.f};
        int row = row0 + r;
        if (row < M) {
            if constexpr (sizeof(TA) == 4) {
                vf = *(const f4*)&A[row * 128 + k4 * 4];
            } else {
                hf4 v = *(const hf4*)&A[row * 128 + k4 * 4];
                vf = f4{(float)v[0], (float)v[1], (float)v[2], (float)v[3]};
            }
        }
        *(f4*)&sA[r][k4 * 4] = vf;
    }
    #pragma unroll
    for (int rep = 0; rep < 8; ++rep) {
        int idx = rep * 256 + tid;       // 0..2047
        int k = idx >> 4, c4 = idx & 15;
        f4 v = *(const f4*)&W[k * 128 + col0 + c4 * 4];
        *(f4*)&sW[k][c4 * 4] = v;
    }
    __syncthreads();

    int tx = tid & 15, ty = tid >> 4;
    float acc[4][4] = {};
    for (int k = 0; k < 128; k += 4) {
        f4 a[4], b[4];
        #pragma unroll
        for (int i = 0; i < 4; ++i) a[i] = *(const f4*)&sA[ty * 4 + i][k];
        #pragma unroll
        for (int kk = 0; kk < 4; ++kk) b[kk] = *(const f4*)&sW[k + kk][tx * 4];
        #pragma unroll
        for (int i = 0; i < 4; ++i)
            #pragma unroll
            for (int j = 0; j < 4; ++j)
                acc[i][j] += a[i][0] * b[0][j] + a[i][1] * b[1][j] +
                             a[i][2] * b[2][j] + a[i][3] * b[3][j];
    }
    #pragma unroll
    for (int i = 0; i < 4; ++i) {
        int row = row0 + ty * 4 + i;
        if (row < M) {
            float dv = dinv[row];
            hf4 o = {(hf)(acc[i][0] * dv), (hf)(acc[i][1] * dv),
                     (hf)(acc[i][2] * dv), (hf)(acc[i][3] * dv)};
            *(hf4*)&out[row * 128 + col0 + tx * 4] = o;
        }
    }
}

// ---------------- quarter-wave gather: 16 lanes per node ----------------
// Row = 256B = 16 lanes x hf8 (dwordx4). Sequential slot order (slot 0 =
// self, slot s>=1 = edge beg+s-1), identical numerics to the round-5 pass.
// Edge ids prefetched in TWO coalesced loads (slots 0..15 / 16..31); the
// source for slot i is selected from both shfl results (no branch).
// 8-deep load ladder -> 32 loads in flight per wave; 16 nodes per block.

__device__ __forceinline__ int get_src(int myE0, int myE1, int gbase, int i) {
    int sA = __shfl(myE0, gbase + (i & 15));
    int sB = __shfl(myE1, gbase + (i & 15));
    return (i < 16) ? sA : sB;
}

#define ACC8(v) do { \
    a0 += (float)(v)[0]; a1 += (float)(v)[1]; a2 += (float)(v)[2]; \
    a3 += (float)(v)[3]; a4 += (float)(v)[4]; a5 += (float)(v)[5]; \
    a6 += (float)(v)[6]; a7 += (float)(v)[7]; } while (0)

template <int MODE>
__global__ __launch_bounds__(256) void agg_k(const hf* __restrict__ xws,
                                             const float* __restrict__ dinv,
                                             const int* __restrict__ rowp,
                                             const int* __restrict__ csr,
                                             const float* __restrict__ bias,
                                             const int* __restrict__ batch,
                                             const float* __restrict__ Wfc,
                                             float* __restrict__ pool,
                                             float* __restrict__ cntp,
                                             hf* __restrict__ h) {
    int tid = threadIdx.x;
    int node = blockIdx.x * 16 + (tid >> 4);   // grid 3125 * 16 = 50000 exact
    int lane = tid & 63;
    int q = lane & 15;          // hf8 slot within 256B row
    int gbase = lane & 48;      // 16-lane group base within wave
    const hf8* rows = (const hf8*)xws;

    int beg = rowp[node], end = rowp[node + 1];
    int cnt = end - beg + 1;    // + self
    // prefetch slots: myE0 = slots 0..15 (0=self), myE1 = slots 16..31
    int myE0 = node;
    if (q > 0) {
        int jj = beg + q - 1;
        if (jj < end) myE0 = csr[jj];
    }
    int myE1 = 0;
    {
        int jj = beg + 15 + q;
        if (jj < end) myE1 = csr[jj];
    }

    float a0 = 0.f, a1 = 0.f, a2 = 0.f, a3 = 0.f;
    float a4 = 0.f, a5 = 0.f, a6 = 0.f, a7 = 0.f;
    int pre = cnt < 32 ? cnt : 32;
    int e = 0;
    for (; e + 8 <= pre; e += 8) {
        int s0 = get_src(myE0, myE1, gbase, e + 0);
        int s1 = get_src(myE0, myE1, gbase, e + 1);
        int s2 = get_src(myE0, myE1, gbase, e + 2);
        int s3 = get_src(myE0, myE1, gbase, e + 3);
        int s4 = get_src(myE0, myE1, gbase, e + 4);
        int s5 = get_src(myE0, myE1, gbase, e + 5);
        int s6 = get_src(myE0, myE1, gbase, e + 6);
        int s7 = get_src(myE0, myE1, gbase, e + 7);
        hf8 v0 = rows[s0 * 16 + q];
        hf8 v1 = rows[s1 * 16 + q];
        hf8 v2 = rows[s2 * 16 + q];
        hf8 v3 = rows[s3 * 16 + q];
        hf8 v4 = rows[s4 * 16 + q];
        hf8 v5 = rows[s5 * 16 + q];
        hf8 v6 = rows[s6 * 16 + q];
        hf8 v7 = rows[s7 * 16 + q];
        ACC8(v0); ACC8(v1); ACC8(v2); ACC8(v3);
        ACC8(v4); ACC8(v5); ACC8(v6); ACC8(v7);
    }
    if (e + 4 <= pre) {
        int s0 = get_src(myE0, myE1, gbase, e + 0);
        int s1 = get_src(myE0, myE1, gbase, e + 1);
        int s2 = get_src(myE0, myE1, gbase, e + 2);
        int s3 = get_src(myE0, myE1, gbase, e + 3);
        hf8 v0 = rows[s0 * 16 + q];
        hf8 v1 = rows[s1 * 16 + q];
        hf8 v2 = rows[s2 * 16 + q];
        hf8 v3 = rows[s3 * 16 + q];
        ACC8(v0); ACC8(v1); ACC8(v2); ACC8(v3);
        e += 4;
    }
    if (e + 2 <= pre) {
        int s0 = get_src(myE0, myE1, gbase, e + 0);
        int s1 = get_src(myE0, myE1, gbase, e + 1);
        hf8 v0 = rows[s0 * 16 + q];
        hf8 v1 = rows[s1 * 16 + q];
        ACC8(v0); ACC8(v1);
        e += 2;
    }
    if (e < pre) {
        int s0 = get_src(myE0, myE1, gbase, e);
        hf8 v0 = rows[s0 * 16 + q];
        ACC8(v0);
    }
    // overflow tail (deg > 31): uniform loads, all 16 lanes same row
    for (int t = beg + 31; t < end; ++t) {
        int s = csr[t];
        hf8 v = rows[s * 16 + q];
        ACC8(v);
    }

    float dn = dinv[node];
    const f4* bias4 = (const f4*)bias;
    f4 bA = bias4[q * 2], bB = bias4[q * 2 + 1];
    float o0 = fmaxf(a0 * dn + bA[0], 0.f);
    float o1 = fmaxf(a1 * dn + bA[1], 0.f);
    float o2 = fmaxf(a2 * dn + bA[2], 0.f);
    float o3 = fmaxf(a3 * dn + bA[3], 0.f);
    float o4 = fmaxf(a4 * dn + bB[0], 0.f);
    float o5 = fmaxf(a5 * dn + bB[1], 0.f);
    float o6 = fmaxf(a6 * dn + bB[2], 0.f);
    float o7 = fmaxf(a7 * dn + bB[3], 0.f);
    if constexpr (MODE == 0) {
        hf8 ov = {(hf)o0, (hf)o1, (hf)o2, (hf)o3,
                  (hf)o4, (hf)o5, (hf)o6, (hf)o7};
        ((hf8*)h)[node * 16 + q] = ov;
    } else {
        const f4* wfc4 = (const f4*)Wfc;
        f4 wA = wfc4[q * 2], wB = wfc4[q * 2 + 1];
        float p = o0 * wA[0] + o1 * wA[1] + o2 * wA[2] + o3 * wA[3] +
                  o4 * wB[0] + o5 * wB[1] + o6 * wB[2] + o7 * wB[3];
        #pragma unroll
        for (int off = 8; off > 0; off >>= 1) p += __shfl_xor(p, off);
        if (q == 0) {
            int g = batch[node];
            atomicAdd(&pool[g], p);
            atomicAdd(&cntp[g], 1.0f);
        }
    }
}

__global__ void finalize_k(const float* __restrict__ pool,
                           const float* __restrict__ cnt,
                           const float* __restrict__ bfc,
                           float* __restrict__ out) {
    int g = blockIdx.x * blockDim.x + threadIdx.x;
    if (g < N_GRAPHS) out[g] = pool[g] / fmaxf(cnt[g], 1.0f) + bfc[0];
}

extern "C" void kernel_launch(void* const* d_in, const int* in_sizes, int n_in,
                              void* d_out, int out_size, void* d_ws, size_t ws_size,
                              hipStream_t stream) {
    const float* x    = (const float*)d_in[0];
    const int*   ei   = (const int*)d_in[1];   // [2, E] flat, int32
    const int*   batch= (const int*)d_in[2];
    const float* W1   = (const float*)d_in[3];
    const float* b1   = (const float*)d_in[4];
    const float* W2   = (const float*)d_in[5];
    const float* b2   = (const float*)d_in[6];
    const float* Wfc  = (const float*)d_in[7];
    const float* bfc  = (const float*)d_in[8];
    float* out = (float*)d_out;

    const int* src = ei;
    const int* dst = ei + N_EDGES;

    // workspace carve-up (segments multiples of 256B; xws rows line-aligned)
    char* w = (char*)d_ws;
    float* dinv   = (float*)w; w += 50048 * 4;
    int*   deg    = (int*)w;   w += 50048 * 4;
    int*   rowp   = (int*)w;   w += 50176 * 4;   // 50001 used, padded
    int*   cursor = (int*)w;   w += 50048 * 4;
    int*   stmp   = (int*)w;   w += 50048 * 4;
    int*   bsum   = (int*)w;   w += 256 * 4;
    int*   csr    = (int*)w;   w += N_EDGES * 4;
    hf*    xws1   = (hf*)w;    w += (size_t)N_NODES * 128 * 2;
    hf*    h1     = (hf*)w;    w += (size_t)N_NODES * 128 * 2;
    hf*    xws2   = (hf*)w;    w += (size_t)N_NODES * 128 * 2;
    float* pool   = (float*)w; w += 512 * 4;
    float* cnt    = (float*)w; w += 512 * 4;

    hipMemsetAsync(deg, 0, N_NODES * sizeof(int), stream);
    hipMemsetAsync(pool, 0, 2 * 512 * sizeof(float), stream);  // pool + cnt

    int eb = (N_EDGES + 255) / 256;
    deg_hist_k<<<eb, 256, 0, stream>>>(dst, deg);

    int nb = (N_NODES + 1023) / 1024;   // 49
    scan1_k<<<nb, 1024, 0, stream>>>(deg, stmp, bsum, N_NODES);
    scan2_k<<<1, 64, 0, stream>>>(bsum, nb);
    scan3_k<<<nb, 1024, 0, stream>>>(stmp, bsum, deg, rowp, cursor, dinv, N_NODES);

    csr_fill_k<<<eb, 256, 0, stream>>>(src, dst, cursor, csr);

    dim3 ggrid((N_NODES + 63) / 64, 2);
    gemm_scaled_k<float><<<ggrid, 256, 0, stream>>>(x, W1, dinv, xws1, N_NODES);

    int gb = N_NODES / 16;   // 3125 blocks, 16 nodes each, exact
    agg_k<0><<<gb, 256, 0, stream>>>(xws1, dinv, rowp, csr, b1,
                                     nullptr, nullptr, nullptr, nullptr, h1);

    gemm_scaled_k<hf><<<ggrid, 256, 0, stream>>>(h1, W2, dinv, xws2, N_NODES);

    agg_k<1><<<gb, 256, 0, stream>>>(xws2, dinv, rowp, csr, b2,
                                     batch, Wfc, pool, cnt, nullptr);

    finalize_k<<<2, 256, 0, stream>>>(pool, cnt, bfc, out);
}

// Round 10
// 330.855 us; speedup vs baseline: 4.4298x; 1.1587x over previous
//
#include <hip/hip_runtime.h>
#include <hip/hip_bf16.h>

typedef float f2 __attribute__((ext_vector_type(2)));
typedef float f4 __attribute__((ext_vector_type(4)));
typedef _Float16 hf;
typedef hf hf2 __attribute__((ext_vector_type(2)));
typedef hf hf4 __attribute__((ext_vector_type(4)));
typedef hf hf8 __attribute__((ext_vector_type(8)));

#define N_NODES 50000
#define N_EDGES 800000
#define CH 128
#define N_GRAPHS 512

// ---------------- degree histogram ----------------
__global__ __launch_bounds__(256) void deg_hist_k(const int* __restrict__ dst,
                                                  int* __restrict__ deg) {
    int e = blockIdx.x * 256 + threadIdx.x;
    if (e < N_EDGES) atomicAdd(&deg[dst[e]], 1);
}

// ---------------- 3-step exclusive scan over 50000 ints ----------------
__global__ __launch_bounds__(1024) void scan1_k(const int* __restrict__ deg,
                                                int* __restrict__ tmp,
                                                int* __restrict__ bsum, int n) {
    __shared__ int s[1024];
    int tid = threadIdx.x;
    int gid = blockIdx.x * 1024 + tid;
    int v = (gid < n) ? deg[gid] : 0;
    s[tid] = v;
    __syncthreads();
    for (int off = 1; off < 1024; off <<= 1) {
        int t = (tid >= off) ? s[tid - off] : 0;
        __syncthreads();
        s[tid] += t;
        __syncthreads();
    }
    if (gid < n) tmp[gid] = s[tid];
    if (tid == 1023) bsum[blockIdx.x] = s[tid];
}

__global__ void scan2_k(int* __restrict__ bsum, int nb) {
    int lane = threadIdx.x;  // one wave of 64
    int v = (lane < nb) ? bsum[lane] : 0;
    for (int off = 1; off < 64; off <<= 1) {
        int t = __shfl_up(v, off);
        if (lane >= off) v += t;
    }
    if (lane < nb) bsum[lane] = v;
}

// writes row_ptr (exclusive), cursor copy, and dinv = rsqrt(deg+1)
__global__ __launch_bounds__(1024) void scan3_k(const int* __restrict__ tmp,
                                                const int* __restrict__ bsum,
                                                const int* __restrict__ deg,
                                                int* __restrict__ rowp,
                                                int* __restrict__ cursor,
                                                float* __restrict__ dinv, int n) {
    int gid = blockIdx.x * 1024 + threadIdx.x;
    if (gid >= n) return;
    int off = blockIdx.x ? bsum[blockIdx.x - 1] : 0;
    int incl = tmp[gid] + off;
    rowp[gid + 1] = incl;
    cursor[gid] = incl - deg[gid];
    dinv[gid] = rsqrtf((float)deg[gid] + 1.0f);  // +1 for self-loop
    if (gid == 0) rowp[0] = 0;
}

// ---------------- CSR fill (src ids bucketed by dst) ----------------
__global__ __launch_bounds__(256) void csr_fill_k(const int* __restrict__ src,
                                                  const int* __restrict__ dst,
                                                  int* __restrict__ cursor,
                                                  int* __restrict__ csr) {
    int e = blockIdx.x * 256 + threadIdx.x;
    if (e < N_EDGES) {
        int d = dst[e];
        int pos = atomicAdd(&cursor[d], 1);
        csr[pos] = src[e];
    }
}

// ------- W frag-pack: wfrag[(ct*4+kc)*64+lane][j] = (hf)W[k][c] -------------
// c = ct*16 + (lane&15), k = kc*32 + (lane>>4)*8 + j. B-operand lane map for
// mfma_f32_16x16x32_f16: col = lane&15, k = (lane>>4)*8 + j (m92/m97 pattern).
__global__ __launch_bounds__(256) void wfrag_k(const float* __restrict__ W,
                                               hf* __restrict__ frag) {
    int gid = blockIdx.x * 256 + threadIdx.x;   // 0..2047
    if (gid >= 2048) return;
    int lane = gid & 63, kc = (gid >> 6) & 3, ct = gid >> 8;
    int c = ct * 16 + (lane & 15);
    int k0 = kc * 32 + ((lane >> 4) & 3) * 8;
    hf8 v;
    #pragma unroll
    for (int j = 0; j < 8; ++j) v[j] = (hf)W[(k0 + j) * 128 + c];
    ((hf8*)frag)[gid] = v;
}

// ------- MFMA GEMM: out[M,128] = (A[M,128] @ W) * dinv[row], fp16 out -------
// Block = 256 thr = 4 waves; wave owns 32 rows (2 x 16-row tiles) x 128 cols.
// A frags direct from global (16B/lane, k-contiguous); B frags from the
// frag-packed wfrag buffer (coalesced 16B/lane, L2-hot). No LDS.
// C/D layout: col = lane&15, row = (lane>>4)*4 + reg  [m89-verified].
template <bool CVT>
__global__ __launch_bounds__(256) void gemm_mfma_k(const void* __restrict__ Av,
                                                   const hf* __restrict__ wfrag,
                                                   const float* __restrict__ dinv,
                                                   hf* __restrict__ out, int M) {
    int wid = threadIdx.x >> 6, lane = threadIdx.x & 63;
    int r0 = blockIdx.x * 128 + wid * 32;
    int rA = lane & 15, g = (lane >> 4) & 3;
    f4 acc[2][8] = {};

    for (int kc = 0; kc < 4; ++kc) {
        int k0 = kc * 32 + g * 8;
        hf8 a0, a1;
        {
            int row = r0 + rA;      if (row > M - 1) row = M - 1;
            int row2 = r0 + 16 + rA; if (row2 > M - 1) row2 = M - 1;
            if constexpr (CVT) {
                const float* ap = (const float*)Av;
                f4 lo = *(const f4*)&ap[(size_t)row * 128 + k0];
                f4 hi = *(const f4*)&ap[(size_t)row * 128 + k0 + 4];
                a0 = hf8{(hf)lo[0], (hf)lo[1], (hf)lo[2], (hf)lo[3],
                         (hf)hi[0], (hf)hi[1], (hf)hi[2], (hf)hi[3]};
                f4 lo2 = *(const f4*)&ap[(size_t)row2 * 128 + k0];
                f4 hi2 = *(const f4*)&ap[(size_t)row2 * 128 + k0 + 4];
                a1 = hf8{(hf)lo2[0], (hf)lo2[1], (hf)lo2[2], (hf)lo2[3],
                         (hf)hi2[0], (hf)hi2[1], (hf)hi2[2], (hf)hi2[3]};
            } else {
                const hf* ap = (const hf*)Av;
                a0 = *(const hf8*)&ap[(size_t)row * 128 + k0];
                a1 = *(const hf8*)&ap[(size_t)row2 * 128 + k0];
            }
        }
        #pragma unroll
        for (int ct = 0; ct < 8; ++ct) {
            hf8 b = *(const hf8*)&wfrag[(size_t)((ct * 4 + kc) * 64 + lane) * 8];
            acc[0][ct] = __builtin_amdgcn_mfma_f32_16x16x32_f16(a0, b,
                                                                acc[0][ct], 0, 0, 0);
            acc[1][ct] = __builtin_amdgcn_mfma_f32_16x16x32_f16(a1, b,
                                                                acc[1][ct], 0, 0, 0);
        }
    }
    // epilogue: scale by dinv[row], store f16
    #pragma unroll
    for (int rt = 0; rt < 2; ++rt) {
        #pragma unroll
        for (int reg = 0; reg < 4; ++reg) {
            int row = r0 + rt * 16 + g * 4 + reg;
            if (row < M) {
                float dv = dinv[row];
                #pragma unroll
                for (int ct = 0; ct < 8; ++ct)
                    out[(size_t)row * 128 + ct * 16 + rA] =
                        (hf)(acc[rt][ct][reg] * dv);
            }
        }
    }
}

// ---------------- half-wave gather core (round-5, best measured) ----------
#define ACC4(v) do { acc[0] += (float)(v)[0]; acc[1] += (float)(v)[1]; \
                     acc[2] += (float)(v)[2]; acc[3] += (float)(v)[3]; } while (0)

__device__ __forceinline__ f4 gather_half(const hf4* __restrict__ rows,
                                          const int* __restrict__ rowp,
                                          const int* __restrict__ csr,
                                          int node, int lane) {
    int hl = lane & 31;          // hf4 slot within 256B row
    int hbase = lane & 32;       // shfl base of this half
    int beg = rowp[node], end = rowp[node + 1];
    int cnt = end - beg + 1;     // + self
    int myE = node;              // slot 0 = self-loop
    if (hl > 0) {
        int j = beg + hl - 1;
        if (j < end) myE = csr[j];
    }
    f4 acc = {0.f, 0.f, 0.f, 0.f};
    int pre = cnt < 32 ? cnt : 32;
    int e = 0;
    for (; e + 8 <= pre; e += 8) {
        int s0 = __shfl(myE, hbase + e + 0);
        int s1 = __shfl(myE, hbase + e + 1);
        int s2 = __shfl(myE, hbase + e + 2);
        int s3 = __shfl(myE, hbase + e + 3);
        int s4 = __shfl(myE, hbase + e + 4);
        int s5 = __shfl(myE, hbase + e + 5);
        int s6 = __shfl(myE, hbase + e + 6);
        int s7 = __shfl(myE, hbase + e + 7);
        hf4 v0 = rows[s0 * 32 + hl];
        hf4 v1 = rows[s1 * 32 + hl];
        hf4 v2 = rows[s2 * 32 + hl];
        hf4 v3 = rows[s3 * 32 + hl];
        hf4 v4 = rows[s4 * 32 + hl];
        hf4 v5 = rows[s5 * 32 + hl];
        hf4 v6 = rows[s6 * 32 + hl];
        hf4 v7 = rows[s7 * 32 + hl];
        ACC4(v0); ACC4(v1); ACC4(v2); ACC4(v3);
        ACC4(v4); ACC4(v5); ACC4(v6); ACC4(v7);
    }
    if (e + 4 <= pre) {
        int s0 = __shfl(myE, hbase + e + 0);
        int s1 = __shfl(myE, hbase + e + 1);
        int s2 = __shfl(myE, hbase + e + 2);
        int s3 = __shfl(myE, hbase + e + 3);
        hf4 v0 = rows[s0 * 32 + hl];
        hf4 v1 = rows[s1 * 32 + hl];
        hf4 v2 = rows[s2 * 32 + hl];
        hf4 v3 = rows[s3 * 32 + hl];
        ACC4(v0); ACC4(v1); ACC4(v2); ACC4(v3);
        e += 4;
    }
    for (; e < pre; ++e) {
        int s0 = __shfl(myE, hbase + e);
        hf4 v0 = rows[s0 * 32 + hl];
        ACC4(v0);
    }
    // overflow tail (deg > 31): uniform loads
    for (int j = beg + 31; j < end; ++j) {
        int s = csr[j];
        hf4 v = rows[s * 32 + hl];
        ACC4(v);
    }
    return acc;
}

// ---------------- layer-1 aggregate: half-wave per node ----------------
__global__ __launch_bounds__(256) void gather1_k(const hf* __restrict__ xws,
                                                 const float* __restrict__ dinv,
                                                 const int* __restrict__ rowp,
                                                 const int* __restrict__ csr,
                                                 const float* __restrict__ bias,
                                                 hf* __restrict__ h) {
    int node = blockIdx.x * 8 + (threadIdx.x >> 5);
    int lane = threadIdx.x & 63;
    int hl = lane & 31;
    f4 acc = gather_half((const hf4*)xws, rowp, csr, node, lane);
    float dn = dinv[node];
    f4 bb = *(const f4*)&bias[hl * 4];
    hf4 o;
    #pragma unroll
    for (int k = 0; k < 4; ++k)
        o[k] = (hf)fmaxf(acc[k] * dn + bb[k], 0.f);
    ((hf4*)h)[node * 32 + hl] = o;
}

// ------- layer-2 aggregate fused with mean-pool dot(Wfc) -------
__global__ __launch_bounds__(256) void gather2_pool_k(const hf* __restrict__ xws,
                                                      const float* __restrict__ dinv,
                                                      const int* __restrict__ rowp,
                                                      const int* __restrict__ csr,
                                                      const float* __restrict__ bias,
                                                      const int* __restrict__ batch,
                                                      const float* __restrict__ Wfc,
                                                      float* __restrict__ pool,
                                                      float* __restrict__ cnt) {
    int node = blockIdx.x * 8 + (threadIdx.x >> 5);
    int lane = threadIdx.x & 63;
    int hl = lane & 31;
    f4 acc = gather_half((const hf4*)xws, rowp, csr, node, lane);
    float dn = dinv[node];
    f4 bb = *(const f4*)&bias[hl * 4];
    f4 wf = *(const f4*)&Wfc[hl * 4];
    float p = 0.f;
    #pragma unroll
    for (int k = 0; k < 4; ++k)
        p += fmaxf(acc[k] * dn + bb[k], 0.f) * wf[k];
    // reduce within the 32-lane half (xor offsets stay inside the half)
    #pragma unroll
    for (int off = 16; off > 0; off >>= 1) p += __shfl_xor(p, off);
    if (hl == 0) {
        int g = batch[node];
        atomicAdd(&pool[g], p);
        atomicAdd(&cnt[g], 1.0f);
    }
}

__global__ void finalize_k(const float* __restrict__ pool,
                           const float* __restrict__ cnt,
                           const float* __restrict__ bfc,
                           float* __restrict__ out) {
    int g = blockIdx.x * blockDim.x + threadIdx.x;
    if (g < N_GRAPHS) out[g] = pool[g] / fmaxf(cnt[g], 1.0f) + bfc[0];
}

extern "C" void kernel_launch(void* const* d_in, const int* in_sizes, int n_in,
                              void* d_out, int out_size, void* d_ws, size_t ws_size,
                              hipStream_t stream) {
    const float* x    = (const float*)d_in[0];
    const int*   ei   = (const int*)d_in[1];   // [2, E] flat, int32
    const int*   batch= (const int*)d_in[2];
    const float* W1   = (const float*)d_in[3];
    const float* b1   = (const float*)d_in[4];
    const float* W2   = (const float*)d_in[5];
    const float* b2   = (const float*)d_in[6];
    const float* Wfc  = (const float*)d_in[7];
    const float* bfc  = (const float*)d_in[8];
    float* out = (float*)d_out;

    const int* src = ei;
    const int* dst = ei + N_EDGES;

    // workspace carve-up (segments multiples of 256B; xws rows line-aligned)
    char* w = (char*)d_ws;
    float* dinv   = (float*)w; w += 50048 * 4;
    int*   deg    = (int*)w;   w += 50048 * 4;
    int*   rowp   = (int*)w;   w += 50176 * 4;   // 50001 used, padded
    int*   cursor = (int*)w;   w += 50048 * 4;
    int*   stmp   = (int*)w;   w += 50048 * 4;
    int*   bsum   = (int*)w;   w += 256 * 4;
    hf*    wf1    = (hf*)w;    w += 16384 * 2;   // frag-packed W1 (32KB)
    hf*    wf2    = (hf*)w;    w += 16384 * 2;   // frag-packed W2 (32KB)
    int*   csr    = (int*)w;   w += N_EDGES * 4;
    hf*    xws1   = (hf*)w;    w += (size_t)N_NODES * 128 * 2;
    hf*    h1     = (hf*)w;    w += (size_t)N_NODES * 128 * 2;
    hf*    xws2   = (hf*)w;    w += (size_t)N_NODES * 128 * 2;
    float* pool   = (float*)w; w += 512 * 4;
    float* cnt    = (float*)w; w += 512 * 4;

    hipMemsetAsync(deg, 0, N_NODES * sizeof(int), stream);
    hipMemsetAsync(pool, 0, 2 * 512 * sizeof(float), stream);  // pool + cnt

    int eb = (N_EDGES + 255) / 256;
    deg_hist_k<<<eb, 256, 0, stream>>>(dst, deg);

    int nb = (N_NODES + 1023) / 1024;   // 49
    scan1_k<<<nb, 1024, 0, stream>>>(deg, stmp, bsum, N_NODES);
    scan2_k<<<1, 64, 0, stream>>>(bsum, nb);
    scan3_k<<<nb, 1024, 0, stream>>>(stmp, bsum, deg, rowp, cursor, dinv, N_NODES);

    csr_fill_k<<<eb, 256, 0, stream>>>(src, dst, cursor, csr);

    wfrag_k<<<8, 256, 0, stream>>>(W1, wf1);
    wfrag_k<<<8, 256, 0, stream>>>(W2, wf2);

    int mg = (N_NODES + 127) / 128;   // 391 blocks
    gemm_mfma_k<true><<<mg, 256, 0, stream>>>(x, wf1, dinv, xws1, N_NODES);

    int gb = N_NODES / 8;   // 6250 blocks, 8 half-waves (nodes) each
    gather1_k<<<gb, 256, 0, stream>>>(xws1, dinv, rowp, csr, b1, h1);

    gemm_mfma_k<false><<<mg, 256, 0, stream>>>(h1, wf2, dinv, xws2, N_NODES);

    gather2_pool_k<<<gb, 256, 0, stream>>>(xws2, dinv, rowp, csr, b2, batch, Wfc,
                                           pool, cnt);

    finalize_k<<<2, 256, 0, stream>>>(pool, cnt, bfc, out);
}